// Round 11
// baseline (324.296 us; speedup 1.0000x reference)
//
#include <hip/hip_runtime.h>
#include <hip/hip_cooperative_groups.h>

namespace cg = cooperative_groups;

#define N_NODES 50000
#define N_EDGES 800000
#define CH 128
#define NBUCK 196          // ceil(50000/256): buckets of 256 dst nodes
#define B_BIN 250          // bin-pass blocks
#define CHUNK 3200         // edges per bin-pass block (250*3200 = 800000)
#define G_GEMM 782         // ceil(50000/64)

typedef __attribute__((ext_vector_type(8))) short bf16x8;
typedef __attribute__((ext_vector_type(8))) unsigned short u16x8;
typedef __attribute__((ext_vector_type(4))) float f32x4;

__device__ __forceinline__ float bf2f(unsigned short u) {
    union { unsigned int i; float f; } c;
    c.i = ((unsigned int)u) << 16;
    return c.f;
}
__device__ __forceinline__ unsigned short f2bf(float f) {
    union { float f; unsigned int i; } c;
    c.f = f;
    unsigned int lsb = (c.i >> 16) & 1u;
    c.i += 0x7fffu + lsb;          // round-to-nearest-even
    return (unsigned short)(c.i >> 16);
}

// ---------------- W transpose to bf16: Wt[n][k] = bf16(W[k][n]); 2 blocks ----------------
__global__ __launch_bounds__(256) void k_wt(const float* __restrict__ Wa,
                                            const float* __restrict__ Wb,
                                            unsigned short* __restrict__ Wta,
                                            unsigned short* __restrict__ Wtb) {
    const float* W = blockIdx.x ? Wb : Wa;
    unsigned short* Wt = blockIdx.x ? Wtb : Wta;
    const int tid = threadIdx.x;
    for (int i = 0; i < 64; ++i) {
        int idx = i * 256 + tid;           // n*128 + k
        int n = idx >> 7, kk = idx & 127;
        Wt[idx] = f2bf(W[kk * CH + n]);
    }
}

// ---------------- mega: blocks [0,B_BIN) = bucket histogram; rest = GEMM1 (unscaled) ----------------
__global__ __launch_bounds__(256) void k_mega(
        const int* __restrict__ ei, int* __restrict__ blk_base,
        const float* __restrict__ X, const unsigned short* __restrict__ Wt1,
        unsigned short* __restrict__ HS1u) {
    const int tid = threadIdx.x;
    const int b = blockIdx.x;

    if (b < B_BIN) {       // ---- bucket histogram ----
        __shared__ int h[NBUCK];
        for (int i = tid; i < NBUCK; i += 256) h[i] = 0;
        __syncthreads();
        const int e0 = b * CHUNK;
        const int* dst = ei + N_EDGES;
        for (int i = tid; i < CHUNK; i += 256)
            atomicAdd(&h[dst[e0 + i] >> 8], 1);
        __syncthreads();
        for (int k = tid; k < NBUCK; k += 256)
            blk_base[b * NBUCK + k] = h[k];
        return;
    }

    // ---- GEMM1 ----
    const int gb = b - B_BIN;
    const int l = tid & 63, w = tid >> 6;
    const int lm = l & 15, lk = l >> 4;
    const int row0 = gb * 64 + w * 16;

    int arow = row0 + lm;
    if (arow >= N_NODES) arow = N_NODES - 1;     // clamp (masked on store)
    bf16x8 a[4];
    #pragma unroll
    for (int ki = 0; ki < 4; ++ki) {
        const float* ap = &X[arow * CH + ki * 32 + lk * 8];
        float4 f0 = *(const float4*)ap;
        float4 f1 = *(const float4*)(ap + 4);
        bf16x8 af;
        af[0] = (short)f2bf(f0.x); af[1] = (short)f2bf(f0.y);
        af[2] = (short)f2bf(f0.z); af[3] = (short)f2bf(f0.w);
        af[4] = (short)f2bf(f1.x); af[5] = (short)f2bf(f1.y);
        af[6] = (short)f2bf(f1.z); af[7] = (short)f2bf(f1.w);
        a[ki] = af;
    }

    #pragma unroll
    for (int ct = 0; ct < 8; ++ct) {
        const unsigned short* wp = &Wt1[(ct * 16 + lm) * CH + lk * 8];
        f32x4 acc = {0.f, 0.f, 0.f, 0.f};
        #pragma unroll
        for (int ki = 0; ki < 4; ++ki) {
            bf16x8 bfrag = *(const bf16x8*)&wp[ki * 32];
            acc = __builtin_amdgcn_mfma_f32_16x16x32_bf16(a[ki], bfrag, acc, 0, 0, 0);
        }
        #pragma unroll
        for (int r = 0; r < 4; ++r) {
            int row = row0 + lk * 4 + r;
            if (row < N_NODES)
                HS1u[row * CH + ct * 16 + lm] = f2bf(acc[r]);
        }
    }
}

// ---------------- cooperative CSR build: colscan | bin-place | counts+rowptr+degc | col-place ----------------
// 256 blocks x 256 threads, all phases in one dispatch. col[e] = (src<<8) | (deg(src)+1).
__global__ __launch_bounds__(256) void k_csr_coop(
        const int* __restrict__ ei, int* __restrict__ blk_base,
        int* __restrict__ bucket_cnt, unsigned int* __restrict__ ebuf,
        int* __restrict__ rowptr, int* __restrict__ degc,
        int* __restrict__ col) {
    cg::grid_group grid = cg::this_grid();
    __shared__ int sm[256];
    __shared__ int aux[NBUCK];     // bbase (P2)
    __shared__ int h[256];         // hist (P2) / cnts (P3)
    __shared__ int fillc[256];
    __shared__ int e0s;
    const int tid = threadIdx.x;
    const int b = blockIdx.x;

    // ---- P1: column scan of per-block bucket counts ----
    if (b < NBUCK) {
        const int k = b;
        int v = (tid < B_BIN) ? blk_base[tid * NBUCK + k] : 0;
        sm[tid] = v;
        __syncthreads();
        #pragma unroll
        for (int off = 1; off < 256; off <<= 1) {
            int t = (tid >= off) ? sm[tid - off] : 0;
            __syncthreads();
            sm[tid] += t;
            __syncthreads();
        }
        if (tid < B_BIN) blk_base[tid * NBUCK + k] = sm[tid] - v;   // exclusive
        if (tid == 255) bucket_cnt[k] = sm[255];
    }
    __threadfence();
    grid.sync();

    // ---- P2: place packed edges into bucket-contiguous ebuf ----
    if (b < B_BIN) {
        int v = (tid < NBUCK) ? bucket_cnt[tid] : 0;
        sm[tid] = v;
        __syncthreads();
        #pragma unroll
        for (int off = 1; off < 256; off <<= 1) {
            int t = (tid >= off) ? sm[tid - off] : 0;
            __syncthreads();
            sm[tid] += t;
            __syncthreads();
        }
        if (tid < NBUCK) aux[tid] = sm[tid] - v;   // bucket base
        for (int i = tid; i < NBUCK; i += 256) h[i] = 0;
        __syncthreads();

        const int e0 = b * CHUNK;
        for (int i = tid; i < CHUNK; i += 256) {
            int s = ei[e0 + i];
            int d = ei[N_EDGES + e0 + i];
            int k = d >> 8;
            int loc = atomicAdd(&h[k], 1);
            int pos = aux[k] + blk_base[b * NBUCK + k] + loc;
            ebuf[pos] = ((unsigned int)s << 8) | (unsigned int)(d & 255);
        }
    }
    __threadfence();
    grid.sync();

    // ---- P3a: per-bucket counts -> rowptr, degc (global); fillc kept in LDS ----
    int e0v = 0, cntv = 0;
    if (b < NBUCK) {
        const int k = b;
        int vb = (tid < NBUCK) ? bucket_cnt[tid] : 0;
        sm[tid] = vb;
        __syncthreads();
        #pragma unroll
        for (int off = 1; off < 256; off <<= 1) {
            int t = (tid >= off) ? sm[tid - off] : 0;
            __syncthreads();
            sm[tid] += t;
            __syncthreads();
        }
        if (tid == k) e0s = sm[tid] - vb;
        h[tid] = 0;                    // cnts
        __syncthreads();
        e0v = e0s;
        cntv = bucket_cnt[k];

        for (int i = tid; i < cntv; i += 256)
            atomicAdd(&h[ebuf[e0v + i] & 255], 1);
        __syncthreads();

        int v = h[tid];
        sm[tid] = v;
        __syncthreads();
        #pragma unroll
        for (int off = 1; off < 256; off <<= 1) {
            int t = (tid >= off) ? sm[tid - off] : 0;
            __syncthreads();
            sm[tid] += t;
            __syncthreads();
        }
        int rp = sm[tid] - v;          // exclusive prefix within bucket
        fillc[tid] = rp;
        int node = (k << 8) + tid;
        if (node < N_NODES) {
            rowptr[node] = e0v + rp;
            int dc = v + 1;            // deg+1 (self loop)
            degc[node] = dc > 255 ? 255 : dc;
        }
        if (k == NBUCK - 1 && tid == 0) rowptr[N_NODES] = N_EDGES;
    }
    __threadfence();
    grid.sync();

    // ---- P3b: placement with degcode from global degc (L2-resident) ----
    if (b < NBUCK) {
        for (int i = tid; i < cntv; i += 256) {
            unsigned int pv = ebuf[e0v + i];
            int s = (int)(pv >> 8);
            int j = pv & 255;
            int loc = atomicAdd(&fillc[j], 1);
            col[e0v + loc] = (s << 8) | degc[s];
        }
    }
}

// ---------------- aggregate: 16 lanes/node, u16x8 per lane, unroll-4 gathers ----------------
// MODE 0 (layer 1, H = unscaled XW1): OUT = bf16( di * relu(di*(di*H[d] + Sum ds*H[s]) + b) )
//   with ds = rsqrt(degcode) unpacked from col — no memory load.
// MODE 1 (layer 2, H = h1p fully scaled): OUT = bf16( di*(H[d] + Sum H[s]) )
template <int MODE>
__global__ __launch_bounds__(256) void k_agg(
        const int* __restrict__ rowptr, const int* __restrict__ col,
        const unsigned short* __restrict__ H,
        const float* __restrict__ b, unsigned short* __restrict__ OUT) {
    int gid = blockIdx.x * 256 + threadIdx.x;   // 3125 blocks * 256 = 800000 exactly
    int node = gid >> 4;
    if (node >= N_NODES) return;
    int lane = gid & 15;
    const u16x8* H8 = (const u16x8*)H;          // 16 u16x8 per 128-ch row

    int e0 = rowptr[node];
    int e1 = rowptr[node + 1];
    float di = rsqrtf((float)(e1 - e0 + 1));    // dinv[node], no memory load

    u16x8 hv = H8[node * 16 + lane];
    float acc[8];
    #pragma unroll
    for (int j = 0; j < 8; ++j)
        acc[j] = MODE == 0 ? bf2f(hv[j]) * di : bf2f(hv[j]);

    int e = e0;
    for (; e + 3 < e1; e += 4) {
        int c0 = col[e], c1 = col[e + 1], c2 = col[e + 2], c3 = col[e + 3];
        u16x8 v0 = H8[(c0 >> 8) * 16 + lane];
        u16x8 v1 = H8[(c1 >> 8) * 16 + lane];
        u16x8 v2 = H8[(c2 >> 8) * 16 + lane];
        u16x8 v3 = H8[(c3 >> 8) * 16 + lane];
        if (MODE == 0) {
            float d0 = rsqrtf((float)(c0 & 255));
            float d1 = rsqrtf((float)(c1 & 255));
            float d2 = rsqrtf((float)(c2 & 255));
            float d3 = rsqrtf((float)(c3 & 255));
            #pragma unroll
            for (int j = 0; j < 8; ++j)
                acc[j] += (bf2f(v0[j]) * d0 + bf2f(v1[j]) * d1)
                        + (bf2f(v2[j]) * d2 + bf2f(v3[j]) * d3);
        } else {
            #pragma unroll
            for (int j = 0; j < 8; ++j)
                acc[j] += (bf2f(v0[j]) + bf2f(v1[j])) + (bf2f(v2[j]) + bf2f(v3[j]));
        }
    }
    for (; e < e1; ++e) {
        int c0 = col[e];
        u16x8 v = H8[(c0 >> 8) * 16 + lane];
        if (MODE == 0) {
            float ds = rsqrtf((float)(c0 & 255));
            #pragma unroll
            for (int j = 0; j < 8; ++j) acc[j] += bf2f(v[j]) * ds;
        } else {
            #pragma unroll
            for (int j = 0; j < 8; ++j) acc[j] += bf2f(v[j]);
        }
    }

    u16x8 o;
    if (MODE == 0) {
        float4 b0 = *(const float4*)&b[lane * 8];
        float4 b1v = *(const float4*)&b[lane * 8 + 4];
        float bb[8] = {b0.x, b0.y, b0.z, b0.w, b1v.x, b1v.y, b1v.z, b1v.w};
        #pragma unroll
        for (int j = 0; j < 8; ++j)
            o[j] = f2bf(fmaxf(acc[j] * di + bb[j], 0.f) * di);
    } else {
        #pragma unroll
        for (int j = 0; j < 8; ++j)
            o[j] = f2bf(acc[j] * di);
    }
    *(u16x8*)&OUT[node * CH + lane * 8] = o;
}

// ---------------- final GEMM: OUT(f32) = relu(A2 @ W2 + b2) ----------------
__global__ __launch_bounds__(256) void k_gemm_out(
        const unsigned short* __restrict__ A2,   // [N][128] bf16 (= Ahat h1, fully scaled)
        const unsigned short* __restrict__ Wt2,  // [128][128] bf16, n-major
        const float* __restrict__ b2,
        float* __restrict__ OUT) {
    const int tid = threadIdx.x;
    const int l = tid & 63, w = tid >> 6;
    const int lm = l & 15, lk = l >> 4;
    const int row0 = blockIdx.x * 64 + w * 16;

    int arow = row0 + lm;
    if (arow >= N_NODES) arow = N_NODES - 1;     // clamp (masked on store)
    bf16x8 a[4];
    #pragma unroll
    for (int ki = 0; ki < 4; ++ki)
        a[ki] = *(const bf16x8*)&A2[arow * CH + ki * 32 + lk * 8];

    #pragma unroll
    for (int ct = 0; ct < 8; ++ct) {
        const unsigned short* wp = &Wt2[(ct * 16 + lm) * CH + lk * 8];
        f32x4 acc = {0.f, 0.f, 0.f, 0.f};
        #pragma unroll
        for (int ki = 0; ki < 4; ++ki) {
            bf16x8 bfrag = *(const bf16x8*)&wp[ki * 32];
            acc = __builtin_amdgcn_mfma_f32_16x16x32_bf16(a[ki], bfrag, acc, 0, 0, 0);
        }
        float bb = b2[ct * 16 + lm];
        #pragma unroll
        for (int r = 0; r < 4; ++r) {
            int row = row0 + lk * 4 + r;
            if (row < N_NODES)
                OUT[row * CH + ct * 16 + lm] = fmaxf(acc[r] + bb, 0.f);
        }
    }
}

extern "C" void kernel_launch(void* const* d_in, const int* in_sizes, int n_in,
                              void* d_out, int out_size, void* d_ws, size_t ws_size,
                              hipStream_t stream) {
    const float* x  = (const float*)d_in[0];
    const int*   ei = (const int*)d_in[1];
    const float* W1 = (const float*)d_in[2];
    const float* b1 = (const float*)d_in[3];
    const float* W2 = (const float*)d_in[4];
    const float* b2 = (const float*)d_in[5];
    float* out = (float*)d_out;

    // workspace layout (4B units):
    int* blk_base    = (int*)d_ws;               // 250*196 = 49000 -> pad 49152
    int* bucket_cnt  = blk_base + 49152;         // 256
    int* rowptr      = bucket_cnt + 256;         // 50001 -> pad 50176
    int* degc        = rowptr + 50176;           // 50176
    int* col         = degc + 50176;             // 800000 -> pad 800256
    unsigned int* ebuf = (unsigned int*)(col + 800256);       // 800000 -> pad 800256
    unsigned short* hs1u = (unsigned short*)(ebuf + 800256);  // 6.4M bf16
    unsigned short* h1p = hs1u + 6400000;                     // 6.4M bf16
    unsigned short* a2  = h1p + 6400000;                      // 6.4M bf16
    unsigned short* wt1 = a2 + 6400000;                       // 16384 bf16
    unsigned short* wt2 = wt1 + 16384;                        // 16384 bf16

    const int gAgg = 3125;      // 50000 nodes * 16 lanes / 256

    k_wt<<<2, 256, 0, stream>>>(W1, W2, wt1, wt2);
    k_mega<<<B_BIN + G_GEMM, 256, 0, stream>>>(ei, blk_base, x, wt1, hs1u);

    {
        const int* ei_ = ei;
        void* args[] = {(void*)&ei_, (void*)&blk_base, (void*)&bucket_cnt,
                        (void*)&ebuf, (void*)&rowptr, (void*)&degc, (void*)&col};
        hipLaunchCooperativeKernel((const void*)k_csr_coop, dim3(256), dim3(256),
                                   args, 0, stream);
    }

    k_agg<0><<<gAgg, 256, 0, stream>>>(rowptr, col, hs1u, b1, h1p);   // h1p = dinv*relu(...)
    k_agg<1><<<gAgg, 256, 0, stream>>>(rowptr, col, h1p, nullptr, a2); // a2 = Ahat h1
    k_gemm_out<<<G_GEMM, 256, 0, stream>>>(a2, wt2, b2, out);
}

// Round 12
// 145.221 us; speedup vs baseline: 2.2331x; 2.2331x over previous
//
#include <hip/hip_runtime.h>

#define N_NODES 50000
#define N_EDGES 800000
#define CH 128
#define NBUCK 196          // ceil(50000/256): buckets of 256 dst nodes
#define B_BIN 250          // bin-pass blocks
#define CHUNK 3200         // edges per bin-pass block (250*3200 = 800000)
#define G_GEMM 782         // ceil(50000/64)

typedef __attribute__((ext_vector_type(8))) short bf16x8;
typedef __attribute__((ext_vector_type(8))) unsigned short u16x8;
typedef __attribute__((ext_vector_type(4))) float f32x4;

__device__ __forceinline__ float bf2f(unsigned short u) {
    union { unsigned int i; float f; } c;
    c.i = ((unsigned int)u) << 16;
    return c.f;
}
__device__ __forceinline__ unsigned short f2bf(float f) {
    union { float f; unsigned int i; } c;
    c.f = f;
    unsigned int lsb = (c.i >> 16) & 1u;
    c.i += 0x7fffu + lsb;          // round-to-nearest-even
    return (unsigned short)(c.i >> 16);
}

// ---------------- W transpose to bf16: Wt[n][k] = bf16(W[k][n]); 2 blocks ----------------
__global__ __launch_bounds__(256) void k_wt(const float* __restrict__ Wa,
                                            const float* __restrict__ Wb,
                                            unsigned short* __restrict__ Wta,
                                            unsigned short* __restrict__ Wtb) {
    const float* W = blockIdx.x ? Wb : Wa;
    unsigned short* Wt = blockIdx.x ? Wtb : Wta;
    const int tid = threadIdx.x;
    for (int i = 0; i < 64; ++i) {
        int idx = i * 256 + tid;           // n*128 + k
        int n = idx >> 7, kk = idx & 127;
        Wt[idx] = f2bf(W[kk * CH + n]);
    }
}

// ---------------- mega: blocks [0,B_BIN) = bucket histogram; rest = GEMM1 (unscaled) ----------------
__global__ __launch_bounds__(256) void k_mega(
        const int* __restrict__ ei, int* __restrict__ blk_base,
        const float* __restrict__ X, const unsigned short* __restrict__ Wt1,
        unsigned short* __restrict__ HS1u) {
    const int tid = threadIdx.x;
    const int b = blockIdx.x;

    if (b < B_BIN) {       // ---- bucket histogram ----
        __shared__ int h[NBUCK];
        for (int i = tid; i < NBUCK; i += 256) h[i] = 0;
        __syncthreads();
        const int e0 = b * CHUNK;
        const int* dst = ei + N_EDGES;
        for (int i = tid; i < CHUNK; i += 256)
            atomicAdd(&h[dst[e0 + i] >> 8], 1);
        __syncthreads();
        for (int k = tid; k < NBUCK; k += 256)
            blk_base[b * NBUCK + k] = h[k];
        return;
    }

    // ---- GEMM1 ----
    const int gb = b - B_BIN;
    const int l = tid & 63, w = tid >> 6;
    const int lm = l & 15, lk = l >> 4;
    const int row0 = gb * 64 + w * 16;

    int arow = row0 + lm;
    if (arow >= N_NODES) arow = N_NODES - 1;     // clamp (masked on store)
    bf16x8 a[4];
    #pragma unroll
    for (int ki = 0; ki < 4; ++ki) {
        const float* ap = &X[arow * CH + ki * 32 + lk * 8];
        float4 f0 = *(const float4*)ap;
        float4 f1 = *(const float4*)(ap + 4);
        bf16x8 af;
        af[0] = (short)f2bf(f0.x); af[1] = (short)f2bf(f0.y);
        af[2] = (short)f2bf(f0.z); af[3] = (short)f2bf(f0.w);
        af[4] = (short)f2bf(f1.x); af[5] = (short)f2bf(f1.y);
        af[6] = (short)f2bf(f1.z); af[7] = (short)f2bf(f1.w);
        a[ki] = af;
    }

    #pragma unroll
    for (int ct = 0; ct < 8; ++ct) {
        const unsigned short* wp = &Wt1[(ct * 16 + lm) * CH + lk * 8];
        f32x4 acc = {0.f, 0.f, 0.f, 0.f};
        #pragma unroll
        for (int ki = 0; ki < 4; ++ki) {
            bf16x8 bfrag = *(const bf16x8*)&wp[ki * 32];
            acc = __builtin_amdgcn_mfma_f32_16x16x32_bf16(a[ki], bfrag, acc, 0, 0, 0);
        }
        #pragma unroll
        for (int r = 0; r < 4; ++r) {
            int row = row0 + lk * 4 + r;
            if (row < N_NODES)
                HS1u[row * CH + ct * 16 + lm] = f2bf(acc[r]);
        }
    }
}

// ---------------- column scan: per bucket k, exclusive-scan counts over the 250 blocks ----------------
__global__ __launch_bounds__(256) void k_colscan(int* __restrict__ blk_base,
                                                 int* __restrict__ bucket_cnt) {
    __shared__ int sm[256];
    const int tid = threadIdx.x, k = blockIdx.x;
    int v = (tid < B_BIN) ? blk_base[tid * NBUCK + k] : 0;
    sm[tid] = v;
    __syncthreads();
    #pragma unroll
    for (int off = 1; off < 256; off <<= 1) {
        int t = (tid >= off) ? sm[tid - off] : 0;
        __syncthreads();
        sm[tid] += t;
        __syncthreads();
    }
    if (tid < B_BIN) blk_base[tid * NBUCK + k] = sm[tid] - v;   // exclusive
    if (tid == 255) bucket_cnt[k] = sm[255];
}

// ---------------- place packed edges into bucket-contiguous ebuf (internal bucket scan) ----------------
__global__ __launch_bounds__(256) void k_bin_place(const int* __restrict__ ei,
                                                   const int* __restrict__ bucket_cnt,
                                                   const int* __restrict__ blk_base,
                                                   unsigned int* __restrict__ ebuf) {
    __shared__ int sm[256];
    __shared__ int bbase[NBUCK];
    __shared__ int h[NBUCK];
    const int tid = threadIdx.x, b = blockIdx.x;

    int v = (tid < NBUCK) ? bucket_cnt[tid] : 0;
    sm[tid] = v;
    __syncthreads();
    #pragma unroll
    for (int off = 1; off < 256; off <<= 1) {
        int t = (tid >= off) ? sm[tid - off] : 0;
        __syncthreads();
        sm[tid] += t;
        __syncthreads();
    }
    if (tid < NBUCK) bbase[tid] = sm[tid] - v;   // exclusive bucket base
    for (int i = tid; i < NBUCK; i += 256) h[i] = 0;
    __syncthreads();

    const int e0 = b * CHUNK;
    for (int i = tid; i < CHUNK; i += 256) {
        int s = ei[e0 + i];
        int d = ei[N_EDGES + e0 + i];
        int k = d >> 8;
        int loc = atomicAdd(&h[k], 1);
        int pos = bbase[k] + blk_base[b * NBUCK + k] + loc;
        ebuf[pos] = ((unsigned int)s << 8) | (unsigned int)(d & 255);
    }
}

// ---------------- per-bucket counts -> rowptr + degc (no placement) ----------------
__global__ __launch_bounds__(256) void k_bucket_cnt(const unsigned int* __restrict__ ebuf,
                                                    const int* __restrict__ bucket_cnt,
                                                    int* __restrict__ rowptr,
                                                    int* __restrict__ degc) {
    __shared__ int cnts[256];
    __shared__ int sm[256];
    __shared__ int e0s;
    const int tid = threadIdx.x, k = blockIdx.x;
    const int node0 = k << 8;

    int vb = (tid < NBUCK) ? bucket_cnt[tid] : 0;
    sm[tid] = vb;
    __syncthreads();
    #pragma unroll
    for (int off = 1; off < 256; off <<= 1) {
        int t = (tid >= off) ? sm[tid - off] : 0;
        __syncthreads();
        sm[tid] += t;
        __syncthreads();
    }
    if (tid == k) e0s = sm[tid] - vb;
    cnts[tid] = 0;
    __syncthreads();
    const int e0 = e0s;
    const int cnt = bucket_cnt[k];

    for (int i = tid; i < cnt; i += 256)
        atomicAdd(&cnts[ebuf[e0 + i] & 255], 1);
    __syncthreads();

    int v = cnts[tid];
    sm[tid] = v;
    __syncthreads();
    #pragma unroll
    for (int off = 1; off < 256; off <<= 1) {
        int t = (tid >= off) ? sm[tid - off] : 0;
        __syncthreads();
        sm[tid] += t;
        __syncthreads();
    }
    int rp = sm[tid] - v;              // exclusive prefix within bucket
    int node = node0 + tid;
    if (node < N_NODES) {
        rowptr[node] = e0 + rp;
        int dc = v + 1;                // deg+1 (self loop)
        degc[node] = dc > 255 ? 255 : dc;
    }
    if (k == NBUCK - 1 && tid == 0) rowptr[N_NODES] = N_EDGES;
}

// ---------------- placement: col[loc] = (src<<8) | degc[src]; fill counters from rowptr ----------------
__global__ __launch_bounds__(256) void k_bucket_place(const unsigned int* __restrict__ ebuf,
                                                      const int* __restrict__ rowptr,
                                                      const int* __restrict__ degc,
                                                      int* __restrict__ col) {
    __shared__ int fillc[256];
    const int tid = threadIdx.x, k = blockIdx.x;
    const int node0 = k << 8;

    int node = node0 + tid;
    fillc[tid] = (node < N_NODES) ? rowptr[node] : N_EDGES;   // absolute positions
    __syncthreads();
    const int e0 = fillc[0];
    const int e1b = (k == NBUCK - 1) ? N_EDGES : rowptr[node0 + 256];
    const int cnt = e1b - e0;

    for (int i = tid; i < cnt; i += 256) {
        unsigned int pv = ebuf[e0 + i];
        int s = (int)(pv >> 8);
        int j = pv & 255;
        int loc = atomicAdd(&fillc[j], 1);
        col[loc] = (s << 8) | degc[s];       // degc L2-resident (200 KB)
    }
}

// ---------------- aggregate: 16 lanes/node, u16x8 per lane, unroll-4 gathers ----------------
// MODE 0 (layer 1, H = unscaled XW1): OUT = bf16( di * relu(di*(di*H[d] + Sum ds*H[s]) + b) )
//   ds = rsqrt(degcode) unpacked from col — no memory load.
// MODE 1 (layer 2, H = h1p fully scaled): OUT = bf16( di*(H[d] + Sum H[s]) )
template <int MODE>
__global__ __launch_bounds__(256) void k_agg(
        const int* __restrict__ rowptr, const int* __restrict__ col,
        const unsigned short* __restrict__ H,
        const float* __restrict__ b, unsigned short* __restrict__ OUT) {
    int gid = blockIdx.x * 256 + threadIdx.x;   // 3125 blocks * 256 = 800000 exactly
    int node = gid >> 4;
    if (node >= N_NODES) return;
    int lane = gid & 15;
    const u16x8* H8 = (const u16x8*)H;          // 16 u16x8 per 128-ch row

    int e0 = rowptr[node];
    int e1 = rowptr[node + 1];
    float di = rsqrtf((float)(e1 - e0 + 1));    // dinv[node], no memory load

    u16x8 hv = H8[node * 16 + lane];
    float acc[8];
    #pragma unroll
    for (int j = 0; j < 8; ++j)
        acc[j] = MODE == 0 ? bf2f(hv[j]) * di : bf2f(hv[j]);

    int e = e0;
    for (; e + 3 < e1; e += 4) {
        int c0 = col[e], c1 = col[e + 1], c2 = col[e + 2], c3 = col[e + 3];
        u16x8 v0 = H8[(c0 >> 8) * 16 + lane];
        u16x8 v1 = H8[(c1 >> 8) * 16 + lane];
        u16x8 v2 = H8[(c2 >> 8) * 16 + lane];
        u16x8 v3 = H8[(c3 >> 8) * 16 + lane];
        if (MODE == 0) {
            float d0 = rsqrtf((float)(c0 & 255));
            float d1 = rsqrtf((float)(c1 & 255));
            float d2 = rsqrtf((float)(c2 & 255));
            float d3 = rsqrtf((float)(c3 & 255));
            #pragma unroll
            for (int j = 0; j < 8; ++j)
                acc[j] += (bf2f(v0[j]) * d0 + bf2f(v1[j]) * d1)
                        + (bf2f(v2[j]) * d2 + bf2f(v3[j]) * d3);
        } else {
            #pragma unroll
            for (int j = 0; j < 8; ++j)
                acc[j] += (bf2f(v0[j]) + bf2f(v1[j])) + (bf2f(v2[j]) + bf2f(v3[j]));
        }
    }
    for (; e < e1; ++e) {
        int c0 = col[e];
        u16x8 v = H8[(c0 >> 8) * 16 + lane];
        if (MODE == 0) {
            float ds = rsqrtf((float)(c0 & 255));
            #pragma unroll
            for (int j = 0; j < 8; ++j) acc[j] += bf2f(v[j]) * ds;
        } else {
            #pragma unroll
            for (int j = 0; j < 8; ++j) acc[j] += bf2f(v[j]);
        }
    }

    u16x8 o;
    if (MODE == 0) {
        float4 b0 = *(const float4*)&b[lane * 8];
        float4 b1v = *(const float4*)&b[lane * 8 + 4];
        float bb[8] = {b0.x, b0.y, b0.z, b0.w, b1v.x, b1v.y, b1v.z, b1v.w};
        #pragma unroll
        for (int j = 0; j < 8; ++j)
            o[j] = f2bf(fmaxf(acc[j] * di + bb[j], 0.f) * di);
    } else {
        #pragma unroll
        for (int j = 0; j < 8; ++j)
            o[j] = f2bf(acc[j] * di);
    }
    *(u16x8*)&OUT[node * CH + lane * 8] = o;
}

// ---------------- final GEMM: OUT(f32) = relu(A2 @ W2 + b2) ----------------
__global__ __launch_bounds__(256) void k_gemm_out(
        const unsigned short* __restrict__ A2,   // [N][128] bf16 (= Ahat h1, fully scaled)
        const unsigned short* __restrict__ Wt2,  // [128][128] bf16, n-major
        const float* __restrict__ b2,
        float* __restrict__ OUT) {
    const int tid = threadIdx.x;
    const int l = tid & 63, w = tid >> 6;
    const int lm = l & 15, lk = l >> 4;
    const int row0 = blockIdx.x * 64 + w * 16;

    int arow = row0 + lm;
    if (arow >= N_NODES) arow = N_NODES - 1;     // clamp (masked on store)
    bf16x8 a[4];
    #pragma unroll
    for (int ki = 0; ki < 4; ++ki)
        a[ki] = *(const bf16x8*)&A2[arow * CH + ki * 32 + lk * 8];

    #pragma unroll
    for (int ct = 0; ct < 8; ++ct) {
        const unsigned short* wp = &Wt2[(ct * 16 + lm) * CH + lk * 8];
        f32x4 acc = {0.f, 0.f, 0.f, 0.f};
        #pragma unroll
        for (int ki = 0; ki < 4; ++ki) {
            bf16x8 bfrag = *(const bf16x8*)&wp[ki * 32];
            acc = __builtin_amdgcn_mfma_f32_16x16x32_bf16(a[ki], bfrag, acc, 0, 0, 0);
        }
        float bb = b2[ct * 16 + lm];
        #pragma unroll
        for (int r = 0; r < 4; ++r) {
            int row = row0 + lk * 4 + r;
            if (row < N_NODES)
                OUT[row * CH + ct * 16 + lm] = fmaxf(acc[r] + bb, 0.f);
        }
    }
}

extern "C" void kernel_launch(void* const* d_in, const int* in_sizes, int n_in,
                              void* d_out, int out_size, void* d_ws, size_t ws_size,
                              hipStream_t stream) {
    const float* x  = (const float*)d_in[0];
    const int*   ei = (const int*)d_in[1];
    const float* W1 = (const float*)d_in[2];
    const float* b1 = (const float*)d_in[3];
    const float* W2 = (const float*)d_in[4];
    const float* b2 = (const float*)d_in[5];
    float* out = (float*)d_out;

    // workspace layout (4B units):
    int* blk_base    = (int*)d_ws;               // 250*196 = 49000 -> pad 49152
    int* bucket_cnt  = blk_base + 49152;         // 256
    int* rowptr      = bucket_cnt + 256;         // 50001 -> pad 50176
    int* degc        = rowptr + 50176;           // 50176
    int* col         = degc + 50176;             // 800000 -> pad 800256
    unsigned int* ebuf = (unsigned int*)(col + 800256);       // 800000 -> pad 800256
    unsigned short* hs1u = (unsigned short*)(ebuf + 800256);  // 6.4M bf16
    unsigned short* h1p = hs1u + 6400000;                     // 6.4M bf16
    unsigned short* a2  = h1p + 6400000;                      // 6.4M bf16
    unsigned short* wt1 = a2 + 6400000;                       // 16384 bf16
    unsigned short* wt2 = wt1 + 16384;                        // 16384 bf16

    const int gAgg = 3125;      // 50000 nodes * 16 lanes / 256

    k_wt<<<2, 256, 0, stream>>>(W1, W2, wt1, wt2);
    k_mega<<<B_BIN + G_GEMM, 256, 0, stream>>>(ei, blk_base, x, wt1, hs1u);
    k_colscan<<<NBUCK, 256, 0, stream>>>(blk_base, bucket_cnt);
    k_bin_place<<<B_BIN, 256, 0, stream>>>(ei, bucket_cnt, blk_base, ebuf);
    k_bucket_cnt<<<NBUCK, 256, 0, stream>>>(ebuf, bucket_cnt, rowptr, degc);
    k_bucket_place<<<NBUCK, 256, 0, stream>>>(ebuf, rowptr, degc, col);
    k_agg<0><<<gAgg, 256, 0, stream>>>(rowptr, col, hs1u, b1, h1p);    // h1p = dinv*relu(...)
    k_agg<1><<<gAgg, 256, 0, stream>>>(rowptr, col, h1p, nullptr, a2); // a2 = Ahat h1
    k_gemm_out<<<G_GEMM, 256, 0, stream>>>(a2, wt2, b2, out);
}

// Round 13
// 142.523 us; speedup vs baseline: 2.2754x; 1.0189x over previous
//
#include <hip/hip_runtime.h>

#define N_NODES 50000
#define N_EDGES 800000
#define CH 128
#define NBUCK 196          // ceil(50000/256): buckets of 256 dst nodes
#define B_BIN 250          // bin-pass blocks
#define CHUNK 3200         // edges per bin-pass block (250*3200 = 800000)
#define G_GEMM 782         // ceil(50000/64)

typedef __attribute__((ext_vector_type(8))) short bf16x8;
typedef __attribute__((ext_vector_type(8))) unsigned short u16x8;
typedef __attribute__((ext_vector_type(4))) float f32x4;

__device__ __forceinline__ float bf2f(unsigned short u) {
    union { unsigned int i; float f; } c;
    c.i = ((unsigned int)u) << 16;
    return c.f;
}
__device__ __forceinline__ unsigned short f2bf(float f) {
    union { float f; unsigned int i; } c;
    c.f = f;
    unsigned int lsb = (c.i >> 16) & 1u;
    c.i += 0x7fffu + lsb;          // round-to-nearest-even
    return (unsigned short)(c.i >> 16);
}

// ---------------- W transpose to bf16: Wt[n][k] = bf16(W[k][n]); 2 blocks ----------------
__global__ __launch_bounds__(256) void k_wt(const float* __restrict__ Wa,
                                            const float* __restrict__ Wb,
                                            unsigned short* __restrict__ Wta,
                                            unsigned short* __restrict__ Wtb) {
    const float* W = blockIdx.x ? Wb : Wa;
    unsigned short* Wt = blockIdx.x ? Wtb : Wta;
    const int tid = threadIdx.x;
    for (int i = 0; i < 64; ++i) {
        int idx = i * 256 + tid;           // n*128 + k
        int n = idx >> 7, kk = idx & 127;
        Wt[idx] = f2bf(W[kk * CH + n]);
    }
}

// ---------------- mega: blocks [0,B_BIN) = bucket histogram; rest = GEMM1 (unscaled) ----------------
__global__ __launch_bounds__(256) void k_mega(
        const int* __restrict__ ei, int* __restrict__ blk_base,
        const float* __restrict__ X, const unsigned short* __restrict__ Wt1,
        unsigned short* __restrict__ HS1u) {
    const int tid = threadIdx.x;
    const int b = blockIdx.x;

    if (b < B_BIN) {       // ---- bucket histogram ----
        __shared__ int h[NBUCK];
        for (int i = tid; i < NBUCK; i += 256) h[i] = 0;
        __syncthreads();
        const int e0 = b * CHUNK;
        const int* dst = ei + N_EDGES;
        for (int i = tid; i < CHUNK; i += 256)
            atomicAdd(&h[dst[e0 + i] >> 8], 1);
        __syncthreads();
        for (int k = tid; k < NBUCK; k += 256)
            blk_base[b * NBUCK + k] = h[k];
        return;
    }

    // ---- GEMM1 ----
    const int gb = b - B_BIN;
    const int l = tid & 63, w = tid >> 6;
    const int lm = l & 15, lk = l >> 4;
    const int row0 = gb * 64 + w * 16;

    int arow = row0 + lm;
    if (arow >= N_NODES) arow = N_NODES - 1;     // clamp (masked on store)
    bf16x8 a[4];
    #pragma unroll
    for (int ki = 0; ki < 4; ++ki) {
        const float* ap = &X[arow * CH + ki * 32 + lk * 8];
        float4 f0 = *(const float4*)ap;
        float4 f1 = *(const float4*)(ap + 4);
        bf16x8 af;
        af[0] = (short)f2bf(f0.x); af[1] = (short)f2bf(f0.y);
        af[2] = (short)f2bf(f0.z); af[3] = (short)f2bf(f0.w);
        af[4] = (short)f2bf(f1.x); af[5] = (short)f2bf(f1.y);
        af[6] = (short)f2bf(f1.z); af[7] = (short)f2bf(f1.w);
        a[ki] = af;
    }

    #pragma unroll
    for (int ct = 0; ct < 8; ++ct) {
        const unsigned short* wp = &Wt1[(ct * 16 + lm) * CH + lk * 8];
        f32x4 acc = {0.f, 0.f, 0.f, 0.f};
        #pragma unroll
        for (int ki = 0; ki < 4; ++ki) {
            bf16x8 bfrag = *(const bf16x8*)&wp[ki * 32];
            acc = __builtin_amdgcn_mfma_f32_16x16x32_bf16(a[ki], bfrag, acc, 0, 0, 0);
        }
        #pragma unroll
        for (int r = 0; r < 4; ++r) {
            int row = row0 + lk * 4 + r;
            if (row < N_NODES)
                HS1u[row * CH + ct * 16 + lm] = f2bf(acc[r]);
        }
    }
}

// ---------------- column scan: per bucket k, exclusive-scan counts over the 250 blocks ----------------
__global__ __launch_bounds__(256) void k_colscan(int* __restrict__ blk_base,
                                                 int* __restrict__ bucket_cnt) {
    __shared__ int sm[256];
    const int tid = threadIdx.x, k = blockIdx.x;
    int v = (tid < B_BIN) ? blk_base[tid * NBUCK + k] : 0;
    sm[tid] = v;
    __syncthreads();
    #pragma unroll
    for (int off = 1; off < 256; off <<= 1) {
        int t = (tid >= off) ? sm[tid - off] : 0;
        __syncthreads();
        sm[tid] += t;
        __syncthreads();
    }
    if (tid < B_BIN) blk_base[tid * NBUCK + k] = sm[tid] - v;   // exclusive
    if (tid == 255) bucket_cnt[k] = sm[255];
}

// ---------------- place packed edges into bucket-contiguous ebuf (internal bucket scan) ----------------
__global__ __launch_bounds__(256) void k_bin_place(const int* __restrict__ ei,
                                                   const int* __restrict__ bucket_cnt,
                                                   const int* __restrict__ blk_base,
                                                   unsigned int* __restrict__ ebuf) {
    __shared__ int sm[256];
    __shared__ int bbase[NBUCK];
    __shared__ int h[NBUCK];
    const int tid = threadIdx.x, b = blockIdx.x;

    int v = (tid < NBUCK) ? bucket_cnt[tid] : 0;
    sm[tid] = v;
    __syncthreads();
    #pragma unroll
    for (int off = 1; off < 256; off <<= 1) {
        int t = (tid >= off) ? sm[tid - off] : 0;
        __syncthreads();
        sm[tid] += t;
        __syncthreads();
    }
    if (tid < NBUCK) bbase[tid] = sm[tid] - v;   // exclusive bucket base
    for (int i = tid; i < NBUCK; i += 256) h[i] = 0;
    __syncthreads();

    const int e0 = b * CHUNK;
    for (int i = tid; i < CHUNK; i += 256) {
        int s = ei[e0 + i];
        int d = ei[N_EDGES + e0 + i];
        int k = d >> 8;
        int loc = atomicAdd(&h[k], 1);
        int pos = bbase[k] + blk_base[b * NBUCK + k] + loc;
        ebuf[pos] = ((unsigned int)s << 8) | (unsigned int)(d & 255);
    }
}

// ---------------- per-bucket CSR: counts -> rowptr + degc(u8); place col = src ----------------
__global__ __launch_bounds__(256) void k_bucket_csr(const unsigned int* __restrict__ ebuf,
                                                    const int* __restrict__ bucket_cnt,
                                                    int* __restrict__ rowptr,
                                                    unsigned char* __restrict__ degc,
                                                    int* __restrict__ col) {
    __shared__ int cnts[256];
    __shared__ int fillc[256];
    __shared__ int sm[256];
    __shared__ int e0s;
    const int tid = threadIdx.x, k = blockIdx.x;
    const int node0 = k << 8;

    int vb = (tid < NBUCK) ? bucket_cnt[tid] : 0;
    sm[tid] = vb;
    __syncthreads();
    #pragma unroll
    for (int off = 1; off < 256; off <<= 1) {
        int t = (tid >= off) ? sm[tid - off] : 0;
        __syncthreads();
        sm[tid] += t;
        __syncthreads();
    }
    if (tid == k) e0s = sm[tid] - vb;
    cnts[tid] = 0;
    __syncthreads();
    const int e0 = e0s;
    const int cnt = bucket_cnt[k];

    for (int i = tid; i < cnt; i += 256)
        atomicAdd(&cnts[ebuf[e0 + i] & 255], 1);
    __syncthreads();

    int v = cnts[tid];
    sm[tid] = v;
    __syncthreads();
    #pragma unroll
    for (int off = 1; off < 256; off <<= 1) {
        int t = (tid >= off) ? sm[tid - off] : 0;
        __syncthreads();
        sm[tid] += t;
        __syncthreads();
    }
    int rp = sm[tid] - v;              // exclusive prefix within bucket
    fillc[tid] = e0 + rp;              // absolute fill cursor
    int node = node0 + tid;
    if (node < N_NODES) {
        rowptr[node] = e0 + rp;
        int dc = v + 1;                // deg+1 (self loop); max deg ~50 at lambda=16
        degc[node] = (unsigned char)(dc > 255 ? 255 : dc);
    }
    if (k == NBUCK - 1 && tid == 0) rowptr[N_NODES] = N_EDGES;
    __syncthreads();

    for (int i = tid; i < cnt; i += 256) {
        unsigned int pv = ebuf[e0 + i];
        int loc = atomicAdd(&fillc[pv & 255], 1);
        col[loc] = (int)(pv >> 8);     // plain src index
    }
}

// ---------------- aggregate: 16 lanes/node, u16x8 per lane, unroll-4 gathers ----------------
// MODE 0 (layer 1, H = unscaled XW1): OUT = bf16( di * relu(di*(di*H[d] + Sum ds*H[s]) + b) )
//   ds = rsqrt(degc[s]) — 1-byte L2-resident load per edge, overlaps the row gather.
// MODE 1 (layer 2, H = h1p fully scaled): OUT = bf16( di*(H[d] + Sum H[s]) )
template <int MODE>
__global__ __launch_bounds__(256) void k_agg(
        const int* __restrict__ rowptr, const int* __restrict__ col,
        const unsigned char* __restrict__ degc,
        const unsigned short* __restrict__ H,
        const float* __restrict__ b, unsigned short* __restrict__ OUT) {
    int gid = blockIdx.x * 256 + threadIdx.x;   // 3125 blocks * 256 = 800000 exactly
    int node = gid >> 4;
    if (node >= N_NODES) return;
    int lane = gid & 15;
    const u16x8* H8 = (const u16x8*)H;          // 16 u16x8 per 128-ch row

    int e0 = rowptr[node];
    int e1 = rowptr[node + 1];
    float di = rsqrtf((float)(e1 - e0 + 1));    // dinv[node], no memory load

    u16x8 hv = H8[node * 16 + lane];
    float acc[8];
    #pragma unroll
    for (int j = 0; j < 8; ++j)
        acc[j] = MODE == 0 ? bf2f(hv[j]) * di : bf2f(hv[j]);

    int e = e0;
    for (; e + 3 < e1; e += 4) {
        int c0 = col[e], c1 = col[e + 1], c2 = col[e + 2], c3 = col[e + 3];
        u16x8 v0 = H8[c0 * 16 + lane];
        u16x8 v1 = H8[c1 * 16 + lane];
        u16x8 v2 = H8[c2 * 16 + lane];
        u16x8 v3 = H8[c3 * 16 + lane];
        if (MODE == 0) {
            float d0 = rsqrtf((float)degc[c0]);
            float d1 = rsqrtf((float)degc[c1]);
            float d2 = rsqrtf((float)degc[c2]);
            float d3 = rsqrtf((float)degc[c3]);
            #pragma unroll
            for (int j = 0; j < 8; ++j)
                acc[j] += (bf2f(v0[j]) * d0 + bf2f(v1[j]) * d1)
                        + (bf2f(v2[j]) * d2 + bf2f(v3[j]) * d3);
        } else {
            #pragma unroll
            for (int j = 0; j < 8; ++j)
                acc[j] += (bf2f(v0[j]) + bf2f(v1[j])) + (bf2f(v2[j]) + bf2f(v3[j]));
        }
    }
    for (; e < e1; ++e) {
        int c0 = col[e];
        u16x8 v = H8[c0 * 16 + lane];
        if (MODE == 0) {
            float ds = rsqrtf((float)degc[c0]);
            #pragma unroll
            for (int j = 0; j < 8; ++j) acc[j] += bf2f(v[j]) * ds;
        } else {
            #pragma unroll
            for (int j = 0; j < 8; ++j) acc[j] += bf2f(v[j]);
        }
    }

    u16x8 o;
    if (MODE == 0) {
        float4 b0 = *(const float4*)&b[lane * 8];
        float4 b1v = *(const float4*)&b[lane * 8 + 4];
        float bb[8] = {b0.x, b0.y, b0.z, b0.w, b1v.x, b1v.y, b1v.z, b1v.w};
        #pragma unroll
        for (int j = 0; j < 8; ++j)
            o[j] = f2bf(fmaxf(acc[j] * di + bb[j], 0.f) * di);
    } else {
        #pragma unroll
        for (int j = 0; j < 8; ++j)
            o[j] = f2bf(acc[j] * di);
    }
    *(u16x8*)&OUT[node * CH + lane * 8] = o;
}

// ---------------- final GEMM: OUT(f32) = relu(A2 @ W2 + b2) ----------------
__global__ __launch_bounds__(256) void k_gemm_out(
        const unsigned short* __restrict__ A2,   // [N][128] bf16 (= Ahat h1, fully scaled)
        const unsigned short* __restrict__ Wt2,  // [128][128] bf16, n-major
        const float* __restrict__ b2,
        float* __restrict__ OUT) {
    const int tid = threadIdx.x;
    const int l = tid & 63, w = tid >> 6;
    const int lm = l & 15, lk = l >> 4;
    const int row0 = blockIdx.x * 64 + w * 16;

    int arow = row0 + lm;
    if (arow >= N_NODES) arow = N_NODES - 1;     // clamp (masked on store)
    bf16x8 a[4];
    #pragma unroll
    for (int ki = 0; ki < 4; ++ki)
        a[ki] = *(const bf16x8*)&A2[arow * CH + ki * 32 + lk * 8];

    #pragma unroll
    for (int ct = 0; ct < 8; ++ct) {
        const unsigned short* wp = &Wt2[(ct * 16 + lm) * CH + lk * 8];
        f32x4 acc = {0.f, 0.f, 0.f, 0.f};
        #pragma unroll
        for (int ki = 0; ki < 4; ++ki) {
            bf16x8 bfrag = *(const bf16x8*)&wp[ki * 32];
            acc = __builtin_amdgcn_mfma_f32_16x16x32_bf16(a[ki], bfrag, acc, 0, 0, 0);
        }
        float bb = b2[ct * 16 + lm];
        #pragma unroll
        for (int r = 0; r < 4; ++r) {
            int row = row0 + lk * 4 + r;
            if (row < N_NODES)
                OUT[row * CH + ct * 16 + lm] = fmaxf(acc[r] + bb, 0.f);
        }
    }
}

extern "C" void kernel_launch(void* const* d_in, const int* in_sizes, int n_in,
                              void* d_out, int out_size, void* d_ws, size_t ws_size,
                              hipStream_t stream) {
    const float* x  = (const float*)d_in[0];
    const int*   ei = (const int*)d_in[1];
    const float* W1 = (const float*)d_in[2];
    const float* b1 = (const float*)d_in[3];
    const float* W2 = (const float*)d_in[4];
    const float* b2 = (const float*)d_in[5];
    float* out = (float*)d_out;

    // workspace layout (4B units):
    int* blk_base    = (int*)d_ws;               // 250*196 = 49000 -> pad 49152
    int* bucket_cnt  = blk_base + 49152;         // 256
    int* rowptr      = bucket_cnt + 256;         // 50001 -> pad 50176
    unsigned char* degc = (unsigned char*)(rowptr + 50176);   // 50176 bytes -> 12544 words
    int* col         = rowptr + 50176 + 12544;   // 800000 -> pad 800256
    unsigned int* ebuf = (unsigned int*)(col + 800256);       // 800000 -> pad 800256
    unsigned short* hs1u = (unsigned short*)(ebuf + 800256);  // 6.4M bf16
    unsigned short* h1p = hs1u + 6400000;                     // 6.4M bf16
    unsigned short* a2  = h1p + 6400000;                      // 6.4M bf16
    unsigned short* wt1 = a2 + 6400000;                       // 16384 bf16
    unsigned short* wt2 = wt1 + 16384;                        // 16384 bf16

    const int gAgg = 3125;      // 50000 nodes * 16 lanes / 256

    k_wt<<<2, 256, 0, stream>>>(W1, W2, wt1, wt2);
    k_mega<<<B_BIN + G_GEMM, 256, 0, stream>>>(ei, blk_base, x, wt1, hs1u);
    k_colscan<<<NBUCK, 256, 0, stream>>>(blk_base, bucket_cnt);
    k_bin_place<<<B_BIN, 256, 0, stream>>>(ei, bucket_cnt, blk_base, ebuf);
    k_bucket_csr<<<NBUCK, 256, 0, stream>>>(ebuf, bucket_cnt, rowptr, degc, col);
    k_agg<0><<<gAgg, 256, 0, stream>>>(rowptr, col, degc, hs1u, b1, h1p);    // h1p = dinv*relu(...)
    k_agg<1><<<gAgg, 256, 0, stream>>>(rowptr, col, degc, h1p, nullptr, a2); // a2 = Ahat h1
    k_gemm_out<<<G_GEMM, 256, 0, stream>>>(a2, wt2, b2, out);
}